// Round 1
// baseline (915.381 us; speedup 1.0000x reference)
//
#include <hip/hip_runtime.h>
#include <math.h>
#include <limits.h>

#define S_N 65536
#define D_N 512
#define B_N 64

// ---------------- workspace layout (float indices) ----------------
#define OFF_SIMS    0
#define OFF_AEXT    (OFF_SIMS + B_N*S_N)        // 96x512: rows 0..63 = normalized new_content, 64..95 = ec_w^T
#define OFF_NORMS   (OFF_AEXT + 96*512)
#define OFF_CONF    (OFF_NORMS + S_N)           // conf_part[s] = sum_j sigmoid(mem.ec_w[:,j]+ec_b[j])*eg_w[32+j]
#define OFF_FLAGS   (OFF_CONF + S_N)            // int: row touched
#define OFF_MASKED  (OFF_FLAGS + S_N)
#define OFF_ERSC    (OFF_MASKED + S_N)
#define OFF_SLOTAGE (OFF_ERSC + S_N)
#define OFF_STORES  (OFF_SLOTAGE + S_N)         // 64
#define OFF_MAXSIM  (OFF_STORES + 64)           // 64 (u32 monotone-coded)
#define OFF_TI      (OFF_MAXSIM + 64)           // 192 int
#define OFF_TV      (OFF_TI + 192)              // 192
#define OFF_APPLY   (OFF_TV + 192)              // 192 int
#define OFF_DNC0    (OFF_APPLY + 192)           // 3*512 (dn_cand for b=0)
#define OFF_DRIFT0  (OFF_DNC0 + 3*512)          // 512
#define OFF_DOCAND  (OFF_DRIFT0 + 512)          // 192*512
#define OFF_SCAL    (OFF_DOCAND + 192*512)      // even -> 8B aligned

// ---------------- output layout (floats) ----------------
#define OUT_MEM 0
#define OUT_AT  (S_N*D_N)
#define OUT_ER  (OUT_AT + S_N)
#define OUT_SS  (OUT_ER + S_N)
#define OUT_NOV (OUT_SS + 64)
#define OUT_RC  (OUT_NOV + 64)

struct __align__(8) Scal {
  unsigned long long victim_pack;
  unsigned long long masked_pack;
  unsigned long long slotage_pack;
  int cnt_active;
  int cond_cnt;
  unsigned age_max_t;
  float nov_mean;
  float changed_sum;
  int do_erase;
  int should_store;
  int write_idx;
  int victim_idx;
};

__device__ __forceinline__ float sigmoidf_(float x){ return 1.0f/(1.0f+expf(-x)); }
__device__ __forceinline__ unsigned f2mono(float f){
  unsigned u = __float_as_uint(f);
  return (u & 0x80000000u) ? ~u : (u | 0x80000000u);
}
__device__ __forceinline__ float mono2f(unsigned m){
  unsigned u = (m & 0x80000000u) ? (m & 0x7FFFFFFFu) : ~m;
  return __uint_as_float(u);
}
// pack (value,index) so u64-max = max value, ties -> lowest index
__device__ __forceinline__ unsigned long long packvi(float v, int i){
  return (((unsigned long long)f2mono(v)) << 32) | (unsigned long long)(0xFFFFFFFFu - (unsigned)i);
}
__device__ __forceinline__ bool betterVI(float v, int i, float v2, int i2){
  return (v > v2) || (v == v2 && i < i2);
}

// ================= k_init: scalars, flags, nn_=normalize(nc), ec^T, age max, at copy =================
__global__ __launch_bounds__(256) void k_init(const float* __restrict__ nc,
                                              const float* __restrict__ at_in,
                                              const float* __restrict__ ec_w,
                                              const int* __restrict__ step_p,
                                              float* __restrict__ ws, float* __restrict__ out){
  int blk = blockIdx.x, t = threadIdx.x;
  Scal* sc = (Scal*)(ws + OFF_SCAL);
  if (blk == 0){
    if (t == 0){
      sc->victim_pack = 0ULL; sc->masked_pack = 0ULL; sc->slotage_pack = 0ULL;
      sc->cnt_active = 0; sc->cond_cnt = 0; sc->age_max_t = 0u;
      sc->nov_mean = 0.0f; sc->changed_sum = 0.0f;
      sc->do_erase = 0; sc->should_store = 0; sc->write_idx = 0; sc->victim_idx = 0;
    }
    if (t < 64) ((unsigned*)(ws + OFF_MAXSIM))[t] = 0u;
  } else if (blk <= 64){
    int b = blk - 1;
    __shared__ float red[256];
    float x0 = nc[b*512 + t], x1 = nc[b*512 + 256 + t];
    red[t] = x0*x0 + x1*x1;
    __syncthreads();
    for (int o=128;o>0;o>>=1){ if (t<o) red[t]+=red[t+o]; __syncthreads(); }
    float inv = 1.0f / fmaxf(sqrtf(red[0]), 1e-12f);
    ws[OFF_AEXT + b*512 + t]       = x0*inv;
    ws[OFF_AEXT + b*512 + 256 + t] = x1*inv;
  } else if (blk <= 96){
    int j = blk - 65;
    for (int d=t; d<512; d+=256) ws[OFF_AEXT + (64+j)*512 + d] = ec_w[d*32 + j];
  } else if (blk <= 160){
    int part = blk - 97;
    float stepf = (float)step_p[0];
    float lmax = -1e30f;
    for (int s = part*1024 + t; s < (part+1)*1024; s += 256)
      lmax = fmaxf(lmax, fmaxf(stepf - at_in[s], 0.0f));
    __shared__ float red[256];
    red[t]=lmax; __syncthreads();
    for (int o=128;o>0;o>>=1){ if (t<o) red[t]=fmaxf(red[t],red[t+o]); __syncthreads(); }
    if (t==0) atomicMax(&sc->age_max_t, f2mono(red[0]));
  } else if (blk <= 224){
    int part = blk - 161;
    for (int s = part*1024 + t; s < (part+1)*1024; s += 256)
      out[OUT_AT + s] = at_in[s];
  } else {
    int part = blk - 225;   // 64 parts
    int* flags = (int*)(ws + OFF_FLAGS);
    for (int s = part*1024 + t; s < (part+1)*1024; s += 256) flags[s] = 0;
  }
}

// ================= k_phase1: fused norms + sims + conf_part + mem copy-out =================
// block = 64 s-rows; A_ext(96x512) x mem_rows(64x512); thread tile 6(a) x 4(s)
__global__ __launch_bounds__(256,2) void k_phase1(const float* __restrict__ mem,
                                                  const float* __restrict__ ec_b,
                                                  const float* __restrict__ eg_w,
                                                  float* __restrict__ ws, float* __restrict__ out){
  __shared__ float lA[96*68];
  __shared__ float lM[64*68];
  __shared__ float linv[64];
  __shared__ unsigned lmax[64];
  int t = threadIdx.x;
  int s0 = blockIdx.x * 64;
  int sg = t & 15, ag = t >> 4;
  float acc[6][4];
  #pragma unroll
  for (int i=0;i<6;i++)
    #pragma unroll
    for (int j=0;j<4;j++) acc[i][j] = 0.0f;
  float ssq = 0.0f;
  if (t < 64) lmax[t] = 0u;
  const float* Aext = ws + OFF_AEXT;

  for (int c=0;c<8;c++){
    __syncthreads();
    #pragma unroll
    for (int r=0;r<24;r++){
      int idx = t + 256*r;
      int row = idx >> 6, col = idx & 63;
      lA[row*68+col] = Aext[row*512 + c*64 + col];
    }
    #pragma unroll
    for (int r=0;r<16;r++){
      int idx = t + 256*r;
      int row = idx >> 6, col = idx & 63;
      float v = mem[(s0+row)*512 + c*64 + col];
      lM[row*68+col] = v;
      out[OUT_MEM + (s0+row)*512 + c*64 + col] = v;
    }
    __syncthreads();
    if (t < 64){
      #pragma unroll 8
      for (int i=0;i<64;i++){ float v = lM[t*68+i]; ssq = fmaf(v,v,ssq); }
    }
    #pragma unroll 2
    for (int d=0; d<64; d++){
      float m0 = lM[(sg     )*68 + d];
      float m1 = lM[(sg + 16)*68 + d];
      float m2 = lM[(sg + 32)*68 + d];
      float m3 = lM[(sg + 48)*68 + d];
      #pragma unroll
      for (int i=0;i<6;i++){
        float a = lA[(ag + 16*i)*68 + d];
        acc[i][0] = fmaf(a, m0, acc[i][0]);
        acc[i][1] = fmaf(a, m1, acc[i][1]);
        acc[i][2] = fmaf(a, m2, acc[i][2]);
        acc[i][3] = fmaf(a, m3, acc[i][3]);
      }
    }
  }
  __syncthreads();
  Scal* sc = (Scal*)(ws + OFF_SCAL);
  if (t < 64){
    float nrm = sqrtf(ssq);
    ws[OFF_NORMS + s0 + t] = nrm;
    linv[t] = 1.0f / fmaxf(nrm, 1e-12f);
    unsigned long long m = __ballot(nrm > 0.5f);
    if (t == 0) atomicAdd(&sc->cnt_active, (int)__popcll(m));
  }
  __syncthreads();
  #pragma unroll
  for (int i=0;i<4;i++){
    int a = ag + 16*i;
    #pragma unroll
    for (int j=0;j<4;j++){
      int scol = sg + 16*j;
      float sim = acc[i][j] * linv[scol];
      ws[OFF_SIMS + a*S_N + s0 + scol] = sim;
      atomicMax(&lmax[a], f2mono(sim));
    }
  }
  // stash conf rows (a=64..95) into lM[32][68]
  #pragma unroll
  for (int i=4;i<6;i++){
    int j = ag + 16*i - 64;
    #pragma unroll
    for (int jj=0;jj<4;jj++){
      int scol = sg + 16*jj;
      lM[j*68 + scol] = acc[i][jj];
    }
  }
  __syncthreads();
  if (t < 64){
    float sum = 0.0f;
    #pragma unroll 8
    for (int j=0;j<32;j++)
      sum += sigmoidf_(lM[j*68 + t] + ec_b[j]) * eg_w[32 + j];
    ws[OFF_CONF + s0 + t] = sum;
    atomicMax(((unsigned*)(ws + OFF_MAXSIM)) + t, lmax[t]);
  }
}

// ================= k_mlp1: store-gate MLP per b (blocks 0..63) + novelty (block 64) =================
__global__ __launch_bounds__(256) void k_mlp1(const float* __restrict__ nc, const float* __restrict__ qr,
    const float* __restrict__ sr_w1, const float* __restrict__ sr_b1,
    const float* __restrict__ sr_g,  const float* __restrict__ sr_beta,
    const float* __restrict__ sr_w2, const float* __restrict__ sr_b2,
    const float* __restrict__ sn_w,  const float* __restrict__ sn_b,
    const float* __restrict__ sg_w,  const float* __restrict__ sg_b,
    float* __restrict__ ws, float* __restrict__ out){
  int b = blockIdx.x, t = threadIdx.x;
  Scal* sc = (Scal*)(ws + OFF_SCAL);
  __shared__ float comb[1024];
  __shared__ float hbuf[256];
  __shared__ float red[256];
  if (b == 64){
    const unsigned* gms = (const unsigned*)(ws + OFF_MAXSIM);
    float nv = 0.0f;
    if (t < 64){
      float msim = mono2f(gms[t]);
      nv = (1.0f - msim) * 0.5f;
      out[OUT_NOV + t] = nv;
    }
    red[t] = (t < 64) ? nv : 0.0f;
    __syncthreads();
    for (int o=128;o>0;o>>=1){ if (t<o) red[t]+=red[t+o]; __syncthreads(); }
    if (t == 0) sc->nov_mean = red[0] / 64.0f;
    return;
  }
  comb[t]       = nc[b*512 + t];
  comb[256 + t] = nc[b*512 + 256 + t];
  comb[512 + t] = qr[b*512 + t];
  comb[768 + t] = qr[b*512 + 256 + t];
  __syncthreads();
  float h = sr_b1[t];
  for (int i=0;i<1024;i++) h = fmaf(comb[i], sr_w1[i*256 + t], h);
  red[t] = h; __syncthreads();
  for (int o=128;o>0;o>>=1){ if (t<o) red[t]+=red[t+o]; __syncthreads(); }
  float mean = red[0] / 256.0f;
  __syncthreads();
  float dx = h - mean;
  red[t] = dx*dx; __syncthreads();
  for (int o=128;o>0;o>>=1){ if (t<o) red[t]+=red[t+o]; __syncthreads(); }
  float var = red[0] / 256.0f;
  __syncthreads();
  float hn = dx / sqrtf(var + 1e-5f) * sr_g[t] + sr_beta[t];
  hbuf[t] = fmaxf(hn, 0.0f);
  __syncthreads();
  float val = 0.0f;
  if (t < 128){
    float r = sr_b2[t];
    for (int j=0;j<256;j++) r = fmaf(hbuf[j], sr_w2[j*128 + t], r);
    r = fmaxf(r, 0.0f);
    float nf = sn_b[t];
    for (int d=0; d<512; d++) nf = fmaf(comb[d], sn_w[d*128 + t], nf);
    nf = sigmoidf_(nf);
    val = (r + nf) * sg_w[t];
  }
  red[t] = val; __syncthreads();
  for (int o=128;o>0;o>>=1){ if (t<o) red[t]+=red[t+o]; __syncthreads(); }
  if (t == 0){
    float ssc = sigmoidf_(red[0] + sg_b[0]);
    out[OUT_SS + b] = ssc;
    ws[OFF_STORES + b] = ssc;
  }
}

// ================= k_scan: cond count + victim argmax =================
__global__ __launch_bounds__(256) void k_scan(const float* __restrict__ at_in,
                                              const int* __restrict__ step_p,
                                              float* __restrict__ ws){
  int t = threadIdx.x;
  Scal* sc = (Scal*)(ws + OFF_SCAL);
  float nov_mean = sc->nov_mean;
  float stepf = (float)step_p[0];
  float agemax = mono2f(sc->age_max_t);
  const float* sims  = ws + OFF_SIMS;
  const float* norms = ws + OFF_NORMS;
  int gid = blockIdx.x*256 + t;
  int gstride = gridDim.x*256;
  int cnt = 0;
  for (int idx = gid; idx < B_N*S_N; idx += gstride){
    float sim = sims[idx];
    int s = idx & (S_N-1);
    if ((nov_mean > 1.0f - sim) && (norms[s] > 0.5f)) cnt++;
  }
  unsigned long long best = 0ULL;
  for (int s = gid; s < S_N; s += gstride){
    float age = fmaxf(stepf - at_in[s], 0.0f);
    float es = age/(agemax + 1e-6f) + (1.0f - sigmoidf_(norms[s]));
    unsigned long long pk = packvi(es, s);
    if (pk > best) best = pk;
  }
  __shared__ int redc[256];
  __shared__ unsigned long long redp[256];
  redc[t] = cnt; redp[t] = best;
  __syncthreads();
  for (int o=128;o>0;o>>=1){
    if (t<o){ redc[t]+=redc[t+o]; if (redp[t+o] > redp[t]) redp[t]=redp[t+o]; }
    __syncthreads();
  }
  if (t == 0){
    atomicAdd(&sc->cond_cnt, redc[0]);
    atomicMax(&sc->victim_pack, redp[0]);
  }
}

// ================= k_victimfix =================
__global__ __launch_bounds__(256) void k_victimfix(const float* __restrict__ ec_b,
                                                   const float* __restrict__ eg_w,
                                                   float* __restrict__ ws, float* __restrict__ out){
  int t = threadIdx.x;
  Scal* sc = (Scal*)(ws + OFF_SCAL);
  float capacity = (float)sc->cnt_active / 65536.0f;
  int de = (capacity > 0.85f) ? 1 : 0;
  int victim = (int)(0xFFFFFFFFu - (unsigned)(sc->victim_pack & 0xFFFFFFFFULL));
  if (t == 0){ sc->do_erase = de; sc->victim_idx = victim; }
  if (de){
    for (int d=t; d<512; d+=256) out[OUT_MEM + victim*512 + d] = 0.0f;
    if (t == 0){
      out[OUT_AT + victim] = -99999.0f;
      ((int*)(ws + OFF_FLAGS))[victim] = 1;
      float sum = 0.0f;
      for (int j=0;j<32;j++) sum += sigmoidf_(ec_b[j]) * eg_w[32 + j];
      ws[OFF_CONF + victim] = sum;
    }
  }
}

// ================= k_top3: per-b top-3 of sims2 (victim column zeroed) =================
__global__ __launch_bounds__(256) void k_top3(float* __restrict__ ws){
  int b = blockIdx.x, t = threadIdx.x;
  Scal* sc = (Scal*)(ws + OFF_SCAL);
  int de = sc->do_erase;
  int victim = sc->victim_idx;
  const float* simrow = ws + OFF_SIMS + b*S_N;
  float v[3] = {-1e30f,-1e30f,-1e30f};
  int ix[3] = {INT_MAX, INT_MAX, INT_MAX};
  for (int s = t; s < S_N; s += 256){
    float val = simrow[s];
    if (de && s == victim) val = 0.0f;
    if (betterVI(val, s, v[2], ix[2])){
      if (betterVI(val, s, v[1], ix[1])){
        if (betterVI(val, s, v[0], ix[0])){
          v[2]=v[1]; ix[2]=ix[1]; v[1]=v[0]; ix[1]=ix[0]; v[0]=val; ix[0]=s;
        } else { v[2]=v[1]; ix[2]=ix[1]; v[1]=val; ix[1]=s; }
      } else { v[2]=val; ix[2]=s; }
    }
  }
  __shared__ float sv[256*3];
  __shared__ int   si[256*3];
  for (int r=0;r<3;r++){ sv[t*3+r]=v[r]; si[t*3+r]=ix[r]; }
  for (int off=128; off>0; off>>=1){
    __syncthreads();
    if (t < off){
      float av[3], bv[3], ov[3]; int ai[3], bi[3], oi[3];
      for (int r=0;r<3;r++){ av[r]=sv[t*3+r]; ai[r]=si[t*3+r]; bv[r]=sv[(t+off)*3+r]; bi[r]=si[(t+off)*3+r]; }
      int ap=0, bp=0;
      for (int r=0;r<3;r++){
        bool takeA = (bp>=3) || (ap<3 && betterVI(av[ap],ai[ap],bv[bp],bi[bp]));
        if (takeA){ ov[r]=av[ap]; oi[r]=ai[ap]; ap++; }
        else      { ov[r]=bv[bp]; oi[r]=bi[bp]; bp++; }
      }
      for (int r=0;r<3;r++){ sv[t*3+r]=ov[r]; si[t*3+r]=oi[r]; }
    }
  }
  __syncthreads();
  if (t == 0){
    for (int k=0;k<3;k++){
      ws[OFF_TV + b*3 + k] = sv[k];
      ((int*)(ws + OFF_TI))[b*3 + k] = si[k];
    }
  }
}

// ================= k_mlp2: dedup MLPs per (b,k); do_cand/dn_cand =================
__global__ __launch_bounds__(256) void k_mlp2(const float* __restrict__ nc,
    const float* __restrict__ dd_w1, const float* __restrict__ dd_b1,
    const float* __restrict__ dd_w2, const float* __restrict__ dd_b2,
    const float* __restrict__ ds_w1, const float* __restrict__ ds_b1,
    const float* __restrict__ ds_w2, const float* __restrict__ ds_b2,
    float* __restrict__ ws, float* __restrict__ out){
  int p = blockIdx.x, t = threadIdx.x;
  int b = p / 3, k = p - 3*b;
  const int* tip = (const int*)(ws + OFF_TI);
  int row = tip[p];
  __shared__ float pairs[1024];
  __shared__ float red[256];
  __shared__ float bc2[2];
  pairs[t]       = nc[b*512 + t];
  pairs[256 + t] = nc[b*512 + 256 + t];
  pairs[512 + t] = out[OUT_MEM + row*512 + t];
  pairs[768 + t] = out[OUT_MEM + row*512 + 256 + t];
  __syncthreads();
  float hd = dd_b1[t], hs = ds_b1[t];
  for (int i=0;i<1024;i++){
    float pv = pairs[i];
    hd = fmaf(pv, dd_w1[i*256 + t], hd);
    hs = fmaf(pv, ds_w1[i*256 + t], hs);
  }
  hd = fmaxf(hd, 0.0f); hs = fmaxf(hs, 0.0f);
  red[t] = hd * dd_w2[t];
  __syncthreads();
  for (int o=128;o>0;o>>=1){ if (t<o) red[t]+=red[t+o]; __syncthreads(); }
  if (t == 0) bc2[0] = red[0] + dd_b2[0];
  __syncthreads();
  red[t] = hs * ds_w2[t];
  __syncthreads();
  for (int o=128;o>0;o>>=1){ if (t<o) red[t]+=red[t+o]; __syncthreads(); }
  if (t == 0) bc2[1] = red[0] + ds_b2[0];
  __syncthreads();
  float prob  = sigmoidf_(bc2[0]);
  float stren = sigmoidf_(bc2[1]);
  float tvv = ws[OFF_TV + p];
  int ap = (tvv > 0.7f && tvv < 0.99f && prob > 0.5f) ? 1 : 0;
  if (t == 0){
    ((int*)(ws + OFF_APPLY))[p] = ap;
    ((int*)(ws + OFF_FLAGS))[row] = 1;   // row is always scatter-written
  }
  for (int d=t; d<512; d+=256){
    float n = pairs[d], g = pairs[512 + d];
    float avg = 0.5f*(n + g);
    ws[OFF_DOCAND + p*512 + d] = (1.0f - stren)*g + stren*avg;
    if (b == 0) ws[OFF_DNC0 + k*512 + d] = (1.0f - stren)*n + stren*avg;
  }
}

// ================= k_scatter: 3 sequential scatters, batch-order last-wins =================
__global__ __launch_bounds__(512) void k_scatter(float* __restrict__ ws, float* __restrict__ out){
  int d = threadIdx.x;  // 512 threads, one column each -> no cross-thread hazards
  const int* tip = (const int*)(ws + OFF_TI);
  const int* ap  = (const int*)(ws + OFF_APPLY);
  for (int k=0;k<3;k++){
    float cur[64];
    #pragma unroll
    for (int b=0;b<64;b++) cur[b] = out[OUT_MEM + tip[b*3 + k]*512 + d];
    #pragma unroll
    for (int b=0;b<64;b++){
      int p = b*3 + k;
      float v = ap[p] ? ws[OFF_DOCAND + p*512 + d] : cur[b];
      out[OUT_MEM + tip[p]*512 + d] = v;
    }
  }
}

// ================= k_erase: erase_scores / masked / slot_age + argmaxes =================
__global__ __launch_bounds__(256) void k_erase(const int* __restrict__ step_p,
    const float* __restrict__ el_w, const float* __restrict__ el_b,
    const float* __restrict__ eg_w, const float* __restrict__ eg_b,
    float* __restrict__ ws, float* __restrict__ out){
  int t = threadIdx.x;
  Scal* sc = (Scal*)(ws + OFF_SCAL);
  float stepf = (float)step_p[0];
  float egb = eg_b[0];
  int gid = blockIdx.x*256 + t;
  int gstride = gridDim.x*256;
  unsigned long long bm = 0ULL, bs = 0ULL;
  for (int s = gid; s < S_N; s += gstride){
    float a = out[OUT_AT + s];
    float x = (stepf - a) / 1000.0f;
    float lp = 0.0f;
    #pragma unroll
    for (int j=0;j<32;j++) lp += fmaxf(x*el_w[j] + el_b[j], 0.0f) * eg_w[j];
    float er = sigmoidf_(lp + ws[OFF_CONF + s] + egb);
    float sa = stepf - a;
    bool recent = (a >= 0.0f) && (sa < 3.0f);
    float msk = recent ? 0.0f : er;
    ws[OFF_ERSC + s] = er;
    ws[OFF_MASKED + s] = msk;
    ws[OFF_SLOTAGE + s] = sa;
    unsigned long long pm = packvi(msk, s); if (pm > bm) bm = pm;
    unsigned long long ps = packvi(sa,  s); if (ps > bs) bs = ps;
  }
  __shared__ unsigned long long rm[256], rs[256];
  rm[t]=bm; rs[t]=bs; __syncthreads();
  for (int o=128;o>0;o>>=1){
    if (t<o){ if (rm[t+o]>rm[t]) rm[t]=rm[t+o]; if (rs[t+o]>rs[t]) rs[t]=rs[t+o]; }
    __syncthreads();
  }
  if (t == 0){
    atomicMax(&sc->masked_pack, rm[0]);
    atomicMax(&sc->slotage_pack, rs[0]);
  }
}

// ================= k_decide: all scalar decisions + drifted_new[0] =================
__global__ __launch_bounds__(64) void k_decide(const float* __restrict__ nc, float* __restrict__ ws){
  int t = threadIdx.x;
  Scal* sc = (Scal*)(ws + OFF_SCAL);
  __shared__ float red[64];
  red[t] = ws[OFF_STORES + t];
  __syncthreads();
  for (int o=32;o>0;o>>=1){ if (t<o) red[t]+=red[t+o]; __syncthreads(); }
  if (t == 0){
    float store_mean = red[0] / 64.0f;
    int cnt = sc->cnt_active;
    float capacity = (float)cnt / 65536.0f;
    float dyn_thr;
    if (capacity < 0.3f) dyn_thr = 0.08f;
    else if (capacity < 0.6f) dyn_thr = 0.08f + (capacity - 0.3f)*0.733f;
    else dyn_thr = 0.3f + (capacity - 0.6f);
    dyn_thr = fminf(fmaxf(dyn_thr, 0.0f), 0.7f);
    float topk_thr = (capacity < 0.3f) ? 0.1f : ((capacity < 0.6f) ? 0.2f : 0.4f);
    float raw_thr  = (capacity < 0.3f) ? 0.3f : 0.5f;
    int base_store = store_mean > raw_thr;
    int novelty_ok = sc->nov_mean > dyn_thr;
    int cmax = cnt > 1 ? cnt : 1;
    float denom = (float)(64 * cmax);
    float perc = (cnt > 0) ? ((float)sc->cond_cnt) / denom : 1.0f;
    int topk_ok = perc > topk_thr;
    int de = sc->do_erase;
    int ss = base_store && novelty_ok && topk_ok;
    if (de && !novelty_ok) ss = 0;
    float mmax = mono2f((unsigned)(sc->masked_pack >> 32));
    int marg = (int)(0xFFFFFFFFu - (unsigned)(sc->masked_pack  & 0xFFFFFFFFULL));
    int sarg = (int)(0xFFFFFFFFu - (unsigned)(sc->slotage_pack & 0xFFFFFFFFULL));
    sc->should_store = ss;
    sc->write_idx = de ? sc->victim_idx : ((mmax > 0.0f) ? marg : sarg);
  }
  __syncthreads();
  const int* ap = (const int*)(ws + OFF_APPLY);
  for (int d=t; d<512; d+=64){
    float v = nc[d];               // b = 0 row
    if (ap[0]) v = ws[OFF_DNC0 + 0*512 + d];
    if (ap[1]) v = ws[OFF_DNC0 + 1*512 + d];
    if (ap[2]) v = ws[OFF_DNC0 + 2*512 + d];
    ws[OFF_DRIFT0 + d] = v;
  }
}

// ================= k_finalout: erase_out + conditional store write =================
__global__ __launch_bounds__(256) void k_finalout(const int* __restrict__ step_p,
                                                  float* __restrict__ ws, float* __restrict__ out){
  int blk = blockIdx.x, t = threadIdx.x;
  Scal* sc = (Scal*)(ws + OFF_SCAL);
  int ss = sc->should_store, de = sc->do_erase;
  if (blk == 64){
    if (ss){
      int wi = sc->write_idx;
      for (int d=t; d<512; d+=256) out[OUT_MEM + wi*512 + d] = ws[OFF_DRIFT0 + d];
      if (t == 0){
        out[OUT_AT + wi] = (float)step_p[0];
        ((int*)(ws + OFF_FLAGS))[wi] = 1;
      }
    }
    return;
  }
  float mmax = mono2f((unsigned)(sc->masked_pack >> 32));
  bool usemask = ss && !de;
  for (int s = blk*256 + t; s < S_N; s += 64*256){
    float v;
    if (usemask) v = (mmax <= 0.0f) ? ws[OFF_SLOTAGE + s] : ws[OFF_MASKED + s];
    else v = ws[OFF_ERSC + s];
    out[OUT_ER + s] = v;
  }
}

// ================= k_diff: |out_mem - mem| over flagged rows only =================
__global__ __launch_bounds__(256) void k_diff(const float* __restrict__ mem,
                                              float* __restrict__ ws, float* __restrict__ out){
  int t = threadIdx.x;
  Scal* sc = (Scal*)(ws + OFF_SCAL);
  const int* flags = (const int*)(ws + OFF_FLAGS);
  float lsum = 0.0f;
  for (int row = blockIdx.x; row < S_N; row += gridDim.x){
    if (flags[row]){
      float part = 0.0f;
      for (int d=t; d<512; d+=256)
        part += fabsf(out[OUT_MEM + row*512 + d] - mem[row*512 + d]);
      lsum += part;
    }
  }
  __shared__ float red[256];
  red[t] = lsum; __syncthreads();
  for (int o=128;o>0;o>>=1){ if (t<o) red[t]+=red[t+o]; __syncthreads(); }
  if (t == 0 && red[0] != 0.0f) atomicAdd(&sc->changed_sum, red[0]);
}

__global__ void k_rc(float* __restrict__ ws, float* __restrict__ out){
  if (threadIdx.x == 0 && blockIdx.x == 0){
    Scal* sc = (Scal*)(ws + OFF_SCAL);
    out[OUT_RC] = sc->changed_sum / 33554432.0f;   // / (S*D)
  }
}

// ================= host =================
extern "C" void kernel_launch(void* const* d_in, const int* in_sizes, int n_in,
                              void* d_out, int out_size, void* d_ws, size_t ws_size,
                              hipStream_t stream) {
  const float* nc    = (const float*)d_in[0];
  const float* qr    = (const float*)d_in[1];
  const float* mem   = (const float*)d_in[2];
  const float* at    = (const float*)d_in[3];
  const int*   step  = (const int*)  d_in[4];
  const float* sr_w1 = (const float*)d_in[5];
  const float* sr_b1 = (const float*)d_in[6];
  const float* sr_g  = (const float*)d_in[7];
  const float* sr_be = (const float*)d_in[8];
  const float* sr_w2 = (const float*)d_in[9];
  const float* sr_b2 = (const float*)d_in[10];
  const float* sn_w  = (const float*)d_in[11];
  const float* sn_b  = (const float*)d_in[12];
  const float* sg_w  = (const float*)d_in[13];
  const float* sg_b  = (const float*)d_in[14];
  const float* el_w  = (const float*)d_in[15];
  const float* el_b  = (const float*)d_in[16];
  const float* ec_w  = (const float*)d_in[17];
  const float* ec_b  = (const float*)d_in[18];
  const float* eg_w  = (const float*)d_in[19];
  const float* eg_b  = (const float*)d_in[20];
  const float* dd_w1 = (const float*)d_in[21];
  const float* dd_b1 = (const float*)d_in[22];
  const float* dd_w2 = (const float*)d_in[23];
  const float* dd_b2 = (const float*)d_in[24];
  const float* ds_w1 = (const float*)d_in[25];
  const float* ds_b1 = (const float*)d_in[26];
  const float* ds_w2 = (const float*)d_in[27];
  const float* ds_b2 = (const float*)d_in[28];
  float* out = (float*)d_out;
  float* ws  = (float*)d_ws;

  k_init     <<<dim3(289), dim3(256), 0, stream>>>(nc, at, ec_w, step, ws, out);
  k_phase1   <<<dim3(1024), dim3(256), 0, stream>>>(mem, ec_b, eg_w, ws, out);
  k_mlp1     <<<dim3(65), dim3(256), 0, stream>>>(nc, qr, sr_w1, sr_b1, sr_g, sr_be,
                                                  sr_w2, sr_b2, sn_w, sn_b, sg_w, sg_b, ws, out);
  k_scan     <<<dim3(512), dim3(256), 0, stream>>>(at, step, ws);
  k_victimfix<<<dim3(1), dim3(256), 0, stream>>>(ec_b, eg_w, ws, out);
  k_top3     <<<dim3(64), dim3(256), 0, stream>>>(ws);
  k_mlp2     <<<dim3(192), dim3(256), 0, stream>>>(nc, dd_w1, dd_b1, dd_w2, dd_b2,
                                                   ds_w1, ds_b1, ds_w2, ds_b2, ws, out);
  k_scatter  <<<dim3(1), dim3(512), 0, stream>>>(ws, out);
  k_erase    <<<dim3(64), dim3(256), 0, stream>>>(step, el_w, el_b, eg_w, eg_b, ws, out);
  k_decide   <<<dim3(1), dim3(64), 0, stream>>>(nc, ws);
  k_finalout <<<dim3(65), dim3(256), 0, stream>>>(step, ws, out);
  k_diff     <<<dim3(256), dim3(256), 0, stream>>>(mem, ws, out);
  k_rc       <<<dim3(1), dim3(64), 0, stream>>>(ws, out);
}

// Round 2
// 583.865 us; speedup vs baseline: 1.5678x; 1.5678x over previous
//
#include <hip/hip_runtime.h>
#include <math.h>
#include <limits.h>

#define S_N 65536
#define D_N 512
#define B_N 64

typedef __attribute__((ext_vector_type(8))) short short8;
typedef __attribute__((ext_vector_type(4))) float f32x4;

// ---------------- workspace layout (float indices) ----------------
#define SIMS_F      (B_N*S_N/2)                 // bf16 sims stored as ushort
#define OFF_SIMS    0
#define OFF_AEXT    (OFF_SIMS + SIMS_F)         // ushort[96*512]: rows 0..63 norm(nc), 64..95 ec_w^T (bf16)
#define AEXT_F      (96*512/2)
#define OFF_NORMS   (OFF_AEXT + AEXT_F)
#define OFF_CONF    (OFF_NORMS + S_N)
#define OFF_FLAGS   (OFF_CONF + S_N)            // int
#define OFF_LIST    (OFF_FLAGS + S_N)           // int[256] touched rows
#define OFF_MASKED  (OFF_LIST + 256)
#define OFF_ERSC    (OFF_MASKED + S_N)
#define OFF_SLOTAGE (OFF_ERSC + S_N)
#define OFF_STORES  (OFF_SLOTAGE + S_N)         // 64
#define OFF_MAXSIM  (OFF_STORES + 64)           // 64 u32 mono
#define OFF_TI      (OFF_MAXSIM + 64)           // 192 int
#define OFF_TV      (OFF_TI + 192)              // 192
#define OFF_APPLY   (OFF_TV + 192)              // 192 int
#define OFF_HM      (OFF_APPLY + 192)           // 2*64*256 mlp1 partials
#define OFF_HNC     (OFF_HM + 32768)            // 2*64*2*256 mlp2 nc-half partials
#define OFF_HG      (OFF_HNC + 65536)           // 2*192*2*256 mlp2 gathered-half partials
#define OFF_DNC0    (OFF_HG + 196608)           // 3*512
#define OFF_DRIFT0  (OFF_DNC0 + 1536)           // 512
#define OFF_DOCAND  (OFF_DRIFT0 + 512)          // 192*512
#define OFF_SCAL    (OFF_DOCAND + 98304)

// ---------------- output layout (floats) ----------------
#define OUT_MEM 0
#define OUT_AT  (S_N*D_N)
#define OUT_ER  (OUT_AT + S_N)
#define OUT_SS  (OUT_ER + S_N)
#define OUT_NOV (OUT_SS + 64)
#define OUT_RC  (OUT_NOV + 64)

struct __align__(8) Scal {
  unsigned long long victim_pack;
  unsigned long long masked_pack;
  unsigned long long slotage_pack;
  int cnt_active;
  int cond_cnt;
  unsigned age_max_t;
  float nov_mean;
  float changed_sum;
  int do_erase;
  int should_store;
  int write_idx;
  int victim_idx;
  int list_cnt;
};

__device__ __forceinline__ float sigmoidf_(float x){ return 1.0f/(1.0f+expf(-x)); }
__device__ __forceinline__ unsigned f2mono(float f){
  unsigned u = __float_as_uint(f);
  return (u & 0x80000000u) ? ~u : (u | 0x80000000u);
}
__device__ __forceinline__ float mono2f(unsigned m){
  unsigned u = (m & 0x80000000u) ? (m & 0x7FFFFFFFu) : ~m;
  return __uint_as_float(u);
}
__device__ __forceinline__ unsigned long long packvi(float v, int i){
  return (((unsigned long long)f2mono(v)) << 32) | (unsigned long long)(0xFFFFFFFFu - (unsigned)i);
}
__device__ __forceinline__ bool betterVI(float v, int i, float v2, int i2){
  return (v > v2) || (v == v2 && i < i2);
}
__device__ __forceinline__ unsigned short bf16r(float f){   // RNE f32->bf16
  unsigned u = __float_as_uint(f);
  return (unsigned short)((u + 0x7fffu + ((u>>16)&1u)) >> 16);
}
__device__ __forceinline__ float bf2f(unsigned short h){
  return __uint_as_float(((unsigned)h)<<16);
}
__device__ __forceinline__ void touch_row(int row, float* ws){
  int* flags = (int*)(ws + OFF_FLAGS);
  if (atomicExch(&flags[row], 1) == 0){
    Scal* sc = (Scal*)(ws + OFF_SCAL);
    int i = atomicAdd(&sc->list_cnt, 1);
    ((int*)(ws + OFF_LIST))[i] = row;
  }
}

// ================= k_init =================
__global__ __launch_bounds__(256) void k_init(const float* __restrict__ nc,
                                              const float* __restrict__ at_in,
                                              const float* __restrict__ ec_w,
                                              const int* __restrict__ step_p,
                                              float* __restrict__ ws, float* __restrict__ out){
  int blk = blockIdx.x, t = threadIdx.x;
  Scal* sc = (Scal*)(ws + OFF_SCAL);
  unsigned short* aB = (unsigned short*)(ws + OFF_AEXT);
  if (blk == 0){
    if (t == 0){
      sc->victim_pack = 0ULL; sc->masked_pack = 0ULL; sc->slotage_pack = 0ULL;
      sc->cnt_active = 0; sc->cond_cnt = 0; sc->age_max_t = 0u;
      sc->nov_mean = 0.0f; sc->changed_sum = 0.0f;
      sc->do_erase = 0; sc->should_store = 0; sc->write_idx = 0; sc->victim_idx = 0;
      sc->list_cnt = 0;
    }
    if (t < 64) ((unsigned*)(ws + OFF_MAXSIM))[t] = 0u;
  } else if (blk <= 64){
    int b = blk - 1;
    __shared__ float red[256];
    float x0 = nc[b*512 + t], x1 = nc[b*512 + 256 + t];
    red[t] = x0*x0 + x1*x1;
    __syncthreads();
    for (int o=128;o>0;o>>=1){ if (t<o) red[t]+=red[t+o]; __syncthreads(); }
    float inv = 1.0f / fmaxf(sqrtf(red[0]), 1e-12f);
    aB[b*512 + t]       = bf16r(x0*inv);
    aB[b*512 + 256 + t] = bf16r(x1*inv);
  } else if (blk <= 96){
    int j = blk - 65;
    for (int d=t; d<512; d+=256) aB[(64+j)*512 + d] = bf16r(ec_w[d*32 + j]);
  } else if (blk <= 160){
    int part = blk - 97;
    float stepf = (float)step_p[0];
    float lmax = -1e30f;
    for (int s = part*1024 + t; s < (part+1)*1024; s += 256)
      lmax = fmaxf(lmax, fmaxf(stepf - at_in[s], 0.0f));
    __shared__ float red[256];
    red[t]=lmax; __syncthreads();
    for (int o=128;o>0;o>>=1){ if (t<o) red[t]=fmaxf(red[t],red[t+o]); __syncthreads(); }
    if (t==0) atomicMax(&sc->age_max_t, f2mono(red[0]));
  } else if (blk <= 224){
    int part = blk - 161;
    for (int s = part*1024 + t; s < (part+1)*1024; s += 256)
      out[OUT_AT + s] = at_in[s];
  } else {
    int part = blk - 225;   // 64 parts
    int* flags = (int*)(ws + OFF_FLAGS);
    for (int s = part*1024 + t; s < (part+1)*1024; s += 256) flags[s] = 0;
  }
}

// ================= k_phase1: MFMA fused norms + sims(bf16) + conf + mem copy-out =================
// block = 64 s-rows; D(96x64) = Aext(96x512,bf16) x Mrows(64x512,bf16)^T ; MFMA 16x16x32
#define BT_ST 520   // LDS B-tile row stride in bf16 elems (512 + 8 pad -> stride 260 dwords == 4 mod 32, 2-way=free)
__global__ __launch_bounds__(256,2) void k_phase1(const float* __restrict__ mem,
                                                  const float* __restrict__ ec_b,
                                                  const float* __restrict__ eg_w,
                                                  float* __restrict__ ws, float* __restrict__ out){
  __shared__ unsigned short lB[64*BT_ST];   // 66560 B -> 2 blocks/CU
  __shared__ float nred[256];
  __shared__ float linv[64];
  __shared__ unsigned lmax[64];
  int t = threadIdx.x;
  int s0 = blockIdx.x * 64;
  if (t < 64) lmax[t] = 0u;
  Scal* sc = (Scal*)(ws + OFF_SCAL);

  // ---- stage: coalesced float4 read, copy-out, bf16 convert into LDS ----
  const float4* mem4 = (const float4*)(mem + (size_t)s0*512);
  float4* out4 = (float4*)(out + OUT_MEM + (size_t)s0*512);
  #pragma unroll
  for (int i=0;i<32;i++){
    int idx = i*256 + t;           // 8192 float4 = 64 rows x 128
    float4 v = mem4[idx];
    out4[idx] = v;
    int row = idx >> 7, c4 = idx & 127;
    unsigned u0 = (((unsigned)bf16r(v.y))<<16) | bf16r(v.x);
    unsigned u1 = (((unsigned)bf16r(v.w))<<16) | bf16r(v.z);
    uint2* dst = (uint2*)&lB[row*BT_ST + c4*4];
    *dst = make_uint2(u0,u1);
  }
  __syncthreads();

  // ---- norms from bf16 tile (precision fine: only thresholds/sigmoid(22) consumers) ----
  {
    int row = t>>2, q = t&3;
    const unsigned* src = (const unsigned*)&lB[row*BT_ST + q*128];
    float ssq = 0.f;
    #pragma unroll
    for (int i=0;i<64;i++){
      unsigned u = src[i];
      float a = __uint_as_float(u<<16);
      float b = __uint_as_float(u & 0xffff0000u);
      ssq = fmaf(a,a,ssq); ssq = fmaf(b,b,ssq);
    }
    nred[t] = ssq;
  }
  __syncthreads();
  if (t < 64){
    float s2 = nred[t*4]+nred[t*4+1]+nred[t*4+2]+nred[t*4+3];
    float nrm = sqrtf(s2);
    ws[OFF_NORMS + s0 + t] = nrm;
    linv[t] = 1.0f / fmaxf(nrm, 1e-12f);
    unsigned long long m = __ballot(nrm > 0.5f);
    if (t == 0) atomicAdd(&sc->cnt_active, (int)__popcll(m));
  }
  __syncthreads();

  // ---- MFMA main: wave w owns s-cols [w*16,w*16+16); 6 row-tiles of A; K=512=16 chunks ----
  int lane = t & 63, wv = t >> 6;
  int quad = lane >> 4, l15 = lane & 15;
  const unsigned short* aB = (const unsigned short*)(ws + OFF_AEXT);
  f32x4 acc[6];
  #pragma unroll
  for (int r=0;r<6;r++) acc[r] = (f32x4){0.f,0.f,0.f,0.f};
  #pragma unroll 4
  for (int kc=0;kc<16;kc++){
    int kb = kc*32 + quad*8;
    short8 bfrag = *(const short8*)&lB[(wv*16 + l15)*BT_ST + kb];
    #pragma unroll
    for (int rt=0;rt<6;rt++){
      short8 afrag = *(const short8*)&aB[(rt*16 + l15)*512 + kb];
      acc[rt] = __builtin_amdgcn_mfma_f32_16x16x32_bf16(afrag, bfrag, acc[rt], 0,0,0);
    }
  }

  // ---- epilogue: D[a][s] col=l15, row=quad*4+reg ----
  float lv = linv[wv*16 + l15];
  unsigned short* simsb = (unsigned short*)(ws + OFF_SIMS);
  #pragma unroll
  for (int rt=0;rt<4;rt++){
    #pragma unroll
    for (int r=0;r<4;r++){
      int a = rt*16 + quad*4 + r;
      float sim = acc[rt][r] * lv;
      simsb[(size_t)a*S_N + s0 + wv*16 + l15] = bf16r(sim);
      atomicMax(&lmax[a], f2mono(sim));
    }
  }
  float cpart = 0.f;
  #pragma unroll
  for (int rt=4;rt<6;rt++){
    #pragma unroll
    for (int r=0;r<4;r++){
      int j = (rt-4)*16 + quad*4 + r;
      cpart += sigmoidf_(acc[rt][r] + ec_b[j]) * eg_w[32+j];
    }
  }
  cpart += __shfl_down(cpart, 32);
  cpart += __shfl_down(cpart, 16);
  if (l15 < 16 && quad == 0) ws[OFF_CONF + s0 + wv*16 + l15] = cpart;
  __syncthreads();
  if (t < 64) atomicMax(((unsigned*)(ws + OFF_MAXSIM)) + t, lmax[t]);
}

// ================= k_mlp1a: h partials (k-split 2) =================
__global__ __launch_bounds__(256) void k_mlp1a(const float* __restrict__ nc, const float* __restrict__ qr,
    const float* __restrict__ sr_w1, float* __restrict__ ws){
  int blk = blockIdx.x, t = threadIdx.x;
  int b = blk >> 1, half = blk & 1;
  __shared__ float ch[512];
  const float* src = half ? qr : nc;
  ch[t] = src[b*512 + t]; ch[256+t] = src[b*512 + 256 + t];
  __syncthreads();
  float h = 0.f;
  const float* w = sr_w1 + (half*512)*256 + t;
  for (int i=0;i<512;i++) h = fmaf(ch[i], w[i*256], h);
  ws[OFF_HM + (half*64 + b)*256 + t] = h;
}

// ================= k_mlp1b: LN + layer2 + store gate; block 64 = novelty =================
__global__ __launch_bounds__(256) void k_mlp1b(const float* __restrict__ nc, const float* __restrict__ qr,
    const float* __restrict__ sr_b1, const float* __restrict__ sr_g, const float* __restrict__ sr_beta,
    const float* __restrict__ sr_w2, const float* __restrict__ sr_b2,
    const float* __restrict__ sn_w,  const float* __restrict__ sn_b,
    const float* __restrict__ sg_w,  const float* __restrict__ sg_b,
    float* __restrict__ ws, float* __restrict__ out){
  int b = blockIdx.x, t = threadIdx.x;
  Scal* sc = (Scal*)(ws + OFF_SCAL);
  __shared__ float red[256];
  if (b == 64){
    const unsigned* gms = (const unsigned*)(ws + OFF_MAXSIM);
    float nv = 0.0f;
    if (t < 64){
      float msim = mono2f(gms[t]);
      nv = (1.0f - msim) * 0.5f;
      out[OUT_NOV + t] = nv;
    }
    red[t] = (t < 64) ? nv : 0.0f;
    __syncthreads();
    for (int o=128;o>0;o>>=1){ if (t<o) red[t]+=red[t+o]; __syncthreads(); }
    if (t == 0) sc->nov_mean = red[0] / 64.0f;
    return;
  }
  __shared__ float comb[1024];
  __shared__ float hbuf[256];
  comb[t]       = nc[b*512 + t];
  comb[256 + t] = nc[b*512 + 256 + t];
  comb[512 + t] = qr[b*512 + t];
  comb[768 + t] = qr[b*512 + 256 + t];
  float h = ws[OFF_HM + b*256 + t] + ws[OFF_HM + (64 + b)*256 + t] + sr_b1[t];
  red[t] = h; __syncthreads();
  for (int o=128;o>0;o>>=1){ if (t<o) red[t]+=red[t+o]; __syncthreads(); }
  float mean = red[0] / 256.0f;
  __syncthreads();
  float dx = h - mean;
  red[t] = dx*dx; __syncthreads();
  for (int o=128;o>0;o>>=1){ if (t<o) red[t]+=red[t+o]; __syncthreads(); }
  float var = red[0] / 256.0f;
  __syncthreads();
  float hn = dx / sqrtf(var + 1e-5f) * sr_g[t] + sr_beta[t];
  hbuf[t] = fmaxf(hn, 0.0f);
  __syncthreads();
  float val = 0.0f;
  if (t < 128){
    float r = sr_b2[t];
    for (int j=0;j<256;j++) r = fmaf(hbuf[j], sr_w2[j*128 + t], r);
    r = fmaxf(r, 0.0f);
    float nf = sn_b[t];
    for (int d=0; d<512; d++) nf = fmaf(comb[d], sn_w[d*128 + t], nf);
    nf = sigmoidf_(nf);
    val = (r + nf) * sg_w[t];
  }
  red[t] = val; __syncthreads();
  for (int o=128;o>0;o>>=1){ if (t<o) red[t]+=red[t+o]; __syncthreads(); }
  if (t == 0){
    float ssc = sigmoidf_(red[0] + sg_b[0]);
    out[OUT_SS + b] = ssc;
    ws[OFF_STORES + b] = ssc;
  }
}

// ================= k_scan: cond count (bf16 sims, uint-packed) + victim argmax =================
__global__ __launch_bounds__(256) void k_scan(const float* __restrict__ at_in,
                                              const int* __restrict__ step_p,
                                              float* __restrict__ ws){
  int t = threadIdx.x;
  Scal* sc = (Scal*)(ws + OFF_SCAL);
  float thr = 1.0f - sc->nov_mean;
  float stepf = (float)step_p[0];
  float agemax = mono2f(sc->age_max_t);
  const unsigned* simsu = (const unsigned*)(ws + OFF_SIMS);
  const float* norms = ws + OFF_NORMS;
  int gid = blockIdx.x*256 + t;
  int gstride = gridDim.x*256;
  int cnt = 0;
  for (int idx = gid; idx < B_N*S_N/2; idx += gstride){
    unsigned u = simsu[idx];
    int s = (idx*2) & (S_N-1);
    float v0 = __uint_as_float(u<<16);
    float v1 = __uint_as_float(u & 0xffff0000u);
    if (v0 > thr && norms[s]   > 0.5f) cnt++;
    if (v1 > thr && norms[s+1] > 0.5f) cnt++;
  }
  unsigned long long best = 0ULL;
  for (int s = gid; s < S_N; s += gstride){
    float age = fmaxf(stepf - at_in[s], 0.0f);
    float es = age/(agemax + 1e-6f) + (1.0f - sigmoidf_(norms[s]));
    unsigned long long pk = packvi(es, s);
    if (pk > best) best = pk;
  }
  __shared__ int redc[256];
  __shared__ unsigned long long redp[256];
  redc[t] = cnt; redp[t] = best;
  __syncthreads();
  for (int o=128;o>0;o>>=1){
    if (t<o){ redc[t]+=redc[t+o]; if (redp[t+o] > redp[t]) redp[t]=redp[t+o]; }
    __syncthreads();
  }
  if (t == 0){
    atomicAdd(&sc->cond_cnt, redc[0]);
    atomicMax(&sc->victim_pack, redp[0]);
  }
}

// ================= k_victimfix =================
__global__ __launch_bounds__(256) void k_victimfix(const float* __restrict__ ec_b,
                                                   const float* __restrict__ eg_w,
                                                   float* __restrict__ ws, float* __restrict__ out){
  int t = threadIdx.x;
  Scal* sc = (Scal*)(ws + OFF_SCAL);
  float capacity = (float)sc->cnt_active / 65536.0f;
  int de = (capacity > 0.85f) ? 1 : 0;
  int victim = (int)(0xFFFFFFFFu - (unsigned)(sc->victim_pack & 0xFFFFFFFFULL));
  if (t == 0){ sc->do_erase = de; sc->victim_idx = victim; }
  if (de){
    for (int d=t; d<512; d+=256) out[OUT_MEM + victim*512 + d] = 0.0f;
    if (t == 0){
      out[OUT_AT + victim] = -99999.0f;
      touch_row(victim, ws);
      float sum = 0.0f;
      for (int j=0;j<32;j++) sum += sigmoidf_(ec_b[j]) * eg_w[32 + j];
      ws[OFF_CONF + victim] = sum;
    }
  }
}

// ================= k_top3: per-b top-3 of sims2 (bf16; victim column zeroed) =================
__global__ __launch_bounds__(256) void k_top3(float* __restrict__ ws){
  int b = blockIdx.x, t = threadIdx.x;
  Scal* sc = (Scal*)(ws + OFF_SCAL);
  int de = sc->do_erase;
  int victim = sc->victim_idx;
  const unsigned short* simrow = (const unsigned short*)(ws + OFF_SIMS) + (size_t)b*S_N;
  float v[3] = {-1e30f,-1e30f,-1e30f};
  int ix[3] = {INT_MAX, INT_MAX, INT_MAX};
  for (int s = t; s < S_N; s += 256){
    float val = bf2f(simrow[s]);
    if (de && s == victim) val = 0.0f;
    if (betterVI(val, s, v[2], ix[2])){
      if (betterVI(val, s, v[1], ix[1])){
        if (betterVI(val, s, v[0], ix[0])){
          v[2]=v[1]; ix[2]=ix[1]; v[1]=v[0]; ix[1]=ix[0]; v[0]=val; ix[0]=s;
        } else { v[2]=v[1]; ix[2]=ix[1]; v[1]=val; ix[1]=s; }
      } else { v[2]=val; ix[2]=s; }
    }
  }
  __shared__ float sv[256*3];
  __shared__ int   si[256*3];
  for (int r=0;r<3;r++){ sv[t*3+r]=v[r]; si[t*3+r]=ix[r]; }
  for (int off=128; off>0; off>>=1){
    __syncthreads();
    if (t < off){
      float av[3], bv[3], ov[3]; int ai[3], bi[3], oi[3];
      for (int r=0;r<3;r++){ av[r]=sv[t*3+r]; ai[r]=si[t*3+r]; bv[r]=sv[(t+off)*3+r]; bi[r]=si[(t+off)*3+r]; }
      int ap=0, bp=0;
      for (int r=0;r<3;r++){
        bool takeA = (bp>=3) || (ap<3 && betterVI(av[ap],ai[ap],bv[bp],bi[bp]));
        if (takeA){ ov[r]=av[ap]; oi[r]=ai[ap]; ap++; }
        else      { ov[r]=bv[bp]; oi[r]=bi[bp]; bp++; }
      }
      for (int r=0;r<3;r++){ sv[t*3+r]=ov[r]; si[t*3+r]=oi[r]; }
    }
  }
  __syncthreads();
  if (t == 0){
    for (int k=0;k<3;k++){
      ws[OFF_TV + b*3 + k] = sv[k];
      ((int*)(ws + OFF_TI))[b*3 + k] = si[k];
    }
  }
}

// ================= k_mlp2: dedup MLP hidden partials, k-split x4 =================
// blk = b*4 + ks. ks 0/1: nc half (pair-shared); ks 2/3: gathered half (3 pairs)
__global__ __launch_bounds__(256) void k_mlp2(const float* __restrict__ nc,
    const float* __restrict__ dd_w1, const float* __restrict__ ds_w1,
    float* __restrict__ ws, float* __restrict__ out){
  int blk = blockIdx.x, t = threadIdx.x;
  int b = blk >> 2, ks = blk & 3;
  __shared__ float ch[3*256];
  if (ks < 2){
    ch[t] = nc[b*512 + ks*256 + t];
    __syncthreads();
    float hd = 0.f, hs = 0.f;
    const float* wd = dd_w1 + (ks*256)*256 + t;
    const float* wq = ds_w1 + (ks*256)*256 + t;
    for (int i=0;i<256;i++){
      float c = ch[i];
      hd = fmaf(c, wd[i*256], hd);
      hs = fmaf(c, wq[i*256], hs);
    }
    float* H = ws + OFF_HNC + ((ks*64 + b)*2)*256;
    H[t] = hd; H[256 + t] = hs;
  } else {
    int ks2 = ks - 2;
    const int* tip = (const int*)(ws + OFF_TI);
    int r0 = tip[b*3], r1 = tip[b*3+1], r2 = tip[b*3+2];
    ch[t]       = out[OUT_MEM + (size_t)r0*512 + ks2*256 + t];
    ch[256 + t] = out[OUT_MEM + (size_t)r1*512 + ks2*256 + t];
    ch[512 + t] = out[OUT_MEM + (size_t)r2*512 + ks2*256 + t];
    __syncthreads();
    float hd0=0,hd1=0,hd2=0,hs0=0,hs1=0,hs2=0;
    const float* wd = dd_w1 + (512 + ks2*256)*256 + t;
    const float* wq = ds_w1 + (512 + ks2*256)*256 + t;
    for (int i=0;i<256;i++){
      float w0 = wd[i*256], w1 = wq[i*256];
      float c0 = ch[i], c1 = ch[256+i], c2 = ch[512+i];
      hd0=fmaf(c0,w0,hd0); hd1=fmaf(c1,w0,hd1); hd2=fmaf(c2,w0,hd2);
      hs0=fmaf(c0,w1,hs0); hs1=fmaf(c1,w1,hs1); hs2=fmaf(c2,w1,hs2);
    }
    float* H = ws + OFF_HG;
    int p0 = b*3;
    H[((ks2*192 + p0+0)*2+0)*256 + t] = hd0;
    H[((ks2*192 + p0+1)*2+0)*256 + t] = hd1;
    H[((ks2*192 + p0+2)*2+0)*256 + t] = hd2;
    H[((ks2*192 + p0+0)*2+1)*256 + t] = hs0;
    H[((ks2*192 + p0+1)*2+1)*256 + t] = hs1;
    H[((ks2*192 + p0+2)*2+1)*256 + t] = hs2;
  }
}

// ================= k_pairfin: combine partials, decide apply, emit candidates =================
__global__ __launch_bounds__(256) void k_pairfin(const float* __restrict__ nc,
    const float* __restrict__ dd_b1, const float* __restrict__ dd_w2, const float* __restrict__ dd_b2,
    const float* __restrict__ ds_b1, const float* __restrict__ ds_w2, const float* __restrict__ ds_b2,
    float* __restrict__ ws, float* __restrict__ out){
  int p = blockIdx.x, t = threadIdx.x;
  int b = p / 3, k = p - 3*b;
  const int* tip = (const int*)(ws + OFF_TI);
  int row = tip[p];
  float hd = ws[OFF_HNC + ((0*64+b)*2+0)*256 + t] + ws[OFF_HNC + ((1*64+b)*2+0)*256 + t]
           + ws[OFF_HG + ((0*192+p)*2+0)*256 + t] + ws[OFF_HG + ((1*192+p)*2+0)*256 + t] + dd_b1[t];
  float hs = ws[OFF_HNC + ((0*64+b)*2+1)*256 + t] + ws[OFF_HNC + ((1*64+b)*2+1)*256 + t]
           + ws[OFF_HG + ((0*192+p)*2+1)*256 + t] + ws[OFF_HG + ((1*192+p)*2+1)*256 + t] + ds_b1[t];
  __shared__ float red[256];
  __shared__ float bc[2];
  red[t] = fmaxf(hd, 0.f) * dd_w2[t];
  __syncthreads();
  for (int o=128;o>0;o>>=1){ if (t<o) red[t]+=red[t+o]; __syncthreads(); }
  if (t == 0) bc[0] = red[0] + dd_b2[0];
  __syncthreads();
  red[t] = fmaxf(hs, 0.f) * ds_w2[t];
  __syncthreads();
  for (int o=128;o>0;o>>=1){ if (t<o) red[t]+=red[t+o]; __syncthreads(); }
  if (t == 0) bc[1] = red[0] + ds_b2[0];
  __syncthreads();
  float prob  = sigmoidf_(bc[0]);
  float stren = sigmoidf_(bc[1]);
  float tvv = ws[OFF_TV + p];
  int ap = (tvv > 0.7f && tvv < 0.99f && prob > 0.5f) ? 1 : 0;
  if (t == 0){
    ((int*)(ws + OFF_APPLY))[p] = ap;
    touch_row(row, ws);
  }
  for (int d=t; d<512; d+=256){
    float n = nc[b*512 + d];
    float g = out[OUT_MEM + (size_t)row*512 + d];
    float avg = 0.5f*(n + g);
    ws[OFF_DOCAND + p*512 + d] = (1.0f - stren)*g + stren*avg;
    if (b == 0) ws[OFF_DNC0 + k*512 + d] = (1.0f - stren)*n + stren*avg;
  }
}

// ================= k_scatter: columns independent; batch order serialized per column =================
__global__ __launch_bounds__(64) void k_scatter(float* __restrict__ ws, float* __restrict__ out){
  int d = blockIdx.x*64 + threadIdx.x;   // 8 blocks x 64 = 512 columns
  const int* tip = (const int*)(ws + OFF_TI);
  const int* ap  = (const int*)(ws + OFF_APPLY);
  for (int k=0;k<3;k++){
    float cur[64];
    #pragma unroll
    for (int b=0;b<64;b++) cur[b] = out[OUT_MEM + (size_t)tip[b*3 + k]*512 + d];
    #pragma unroll
    for (int b=0;b<64;b++){
      int p = b*3 + k;
      float v = ap[p] ? ws[OFF_DOCAND + p*512 + d] : cur[b];
      out[OUT_MEM + (size_t)tip[p]*512 + d] = v;
    }
  }
}

// ================= k_erase =================
__global__ __launch_bounds__(256) void k_erase(const int* __restrict__ step_p,
    const float* __restrict__ el_w, const float* __restrict__ el_b,
    const float* __restrict__ eg_w, const float* __restrict__ eg_b,
    float* __restrict__ ws, float* __restrict__ out){
  int t = threadIdx.x;
  Scal* sc = (Scal*)(ws + OFF_SCAL);
  float stepf = (float)step_p[0];
  float egb = eg_b[0];
  int gid = blockIdx.x*256 + t;
  int gstride = gridDim.x*256;
  unsigned long long bm = 0ULL, bs = 0ULL;
  for (int s = gid; s < S_N; s += gstride){
    float a = out[OUT_AT + s];
    float x = (stepf - a) / 1000.0f;
    float lp = 0.0f;
    #pragma unroll
    for (int j=0;j<32;j++) lp += fmaxf(x*el_w[j] + el_b[j], 0.0f) * eg_w[j];
    float er = sigmoidf_(lp + ws[OFF_CONF + s] + egb);
    float sa = stepf - a;
    bool recent = (a >= 0.0f) && (sa < 3.0f);
    float msk = recent ? 0.0f : er;
    ws[OFF_ERSC + s] = er;
    ws[OFF_MASKED + s] = msk;
    ws[OFF_SLOTAGE + s] = sa;
    unsigned long long pm = packvi(msk, s); if (pm > bm) bm = pm;
    unsigned long long ps = packvi(sa,  s); if (ps > bs) bs = ps;
  }
  __shared__ unsigned long long rm[256], rs[256];
  rm[t]=bm; rs[t]=bs; __syncthreads();
  for (int o=128;o>0;o>>=1){
    if (t<o){ if (rm[t+o]>rm[t]) rm[t]=rm[t+o]; if (rs[t+o]>rs[t]) rs[t]=rs[t+o]; }
    __syncthreads();
  }
  if (t == 0){
    atomicMax(&sc->masked_pack, rm[0]);
    atomicMax(&sc->slotage_pack, rs[0]);
  }
}

// ================= k_decide =================
__global__ __launch_bounds__(64) void k_decide(const float* __restrict__ nc, float* __restrict__ ws){
  int t = threadIdx.x;
  Scal* sc = (Scal*)(ws + OFF_SCAL);
  __shared__ float red[64];
  red[t] = ws[OFF_STORES + t];
  __syncthreads();
  for (int o=32;o>0;o>>=1){ if (t<o) red[t]+=red[t+o]; __syncthreads(); }
  if (t == 0){
    float store_mean = red[0] / 64.0f;
    int cnt = sc->cnt_active;
    float capacity = (float)cnt / 65536.0f;
    float dyn_thr;
    if (capacity < 0.3f) dyn_thr = 0.08f;
    else if (capacity < 0.6f) dyn_thr = 0.08f + (capacity - 0.3f)*0.733f;
    else dyn_thr = 0.3f + (capacity - 0.6f);
    dyn_thr = fminf(fmaxf(dyn_thr, 0.0f), 0.7f);
    float topk_thr = (capacity < 0.3f) ? 0.1f : ((capacity < 0.6f) ? 0.2f : 0.4f);
    float raw_thr  = (capacity < 0.3f) ? 0.3f : 0.5f;
    int base_store = store_mean > raw_thr;
    int novelty_ok = sc->nov_mean > dyn_thr;
    int cmax = cnt > 1 ? cnt : 1;
    float denom = (float)(64 * cmax);
    float perc = (cnt > 0) ? ((float)sc->cond_cnt) / denom : 1.0f;
    int topk_ok = perc > topk_thr;
    int de = sc->do_erase;
    int ss = base_store && novelty_ok && topk_ok;
    if (de && !novelty_ok) ss = 0;
    float mmax = mono2f((unsigned)(sc->masked_pack >> 32));
    int marg = (int)(0xFFFFFFFFu - (unsigned)(sc->masked_pack  & 0xFFFFFFFFULL));
    int sarg = (int)(0xFFFFFFFFu - (unsigned)(sc->slotage_pack & 0xFFFFFFFFULL));
    sc->should_store = ss;
    sc->write_idx = de ? sc->victim_idx : ((mmax > 0.0f) ? marg : sarg);
  }
  __syncthreads();
  const int* ap = (const int*)(ws + OFF_APPLY);
  for (int d=t; d<512; d+=64){
    float v = nc[d];               // b = 0 row
    if (ap[0]) v = ws[OFF_DNC0 + 0*512 + d];
    if (ap[1]) v = ws[OFF_DNC0 + 1*512 + d];
    if (ap[2]) v = ws[OFF_DNC0 + 2*512 + d];
    ws[OFF_DRIFT0 + d] = v;
  }
}

// ================= k_finalout =================
__global__ __launch_bounds__(256) void k_finalout(const int* __restrict__ step_p,
                                                  float* __restrict__ ws, float* __restrict__ out){
  int blk = blockIdx.x, t = threadIdx.x;
  Scal* sc = (Scal*)(ws + OFF_SCAL);
  int ss = sc->should_store, de = sc->do_erase;
  if (blk == 64){
    if (ss){
      int wi = sc->write_idx;
      for (int d=t; d<512; d+=256) out[OUT_MEM + (size_t)wi*512 + d] = ws[OFF_DRIFT0 + d];
      if (t == 0){
        out[OUT_AT + wi] = (float)step_p[0];
        touch_row(wi, ws);
      }
    }
    return;
  }
  float mmax = mono2f((unsigned)(sc->masked_pack >> 32));
  bool usemask = ss && !de;
  for (int s = blk*256 + t; s < S_N; s += 64*256){
    float v;
    if (usemask) v = (mmax <= 0.0f) ? ws[OFF_SLOTAGE + s] : ws[OFF_MASKED + s];
    else v = ws[OFF_ERSC + s];
    out[OUT_ER + s] = v;
  }
}

// ================= k_diff: |out_mem - mem| over touched rows only (<=194) =================
__global__ __launch_bounds__(256) void k_diff(const float* __restrict__ mem,
                                              float* __restrict__ ws, float* __restrict__ out){
  int t = threadIdx.x;
  Scal* sc = (Scal*)(ws + OFF_SCAL);
  int cnt = sc->list_cnt;
  const int* list = (const int*)(ws + OFF_LIST);
  float lsum = 0.0f;
  for (int i = blockIdx.x; i < cnt; i += gridDim.x){
    int row = list[i];
    float part = 0.0f;
    for (int d=t; d<512; d+=256)
      part += fabsf(out[OUT_MEM + (size_t)row*512 + d] - mem[(size_t)row*512 + d]);
    lsum += part;
  }
  __shared__ float red[256];
  red[t] = lsum; __syncthreads();
  for (int o=128;o>0;o>>=1){ if (t<o) red[t]+=red[t+o]; __syncthreads(); }
  if (t == 0 && red[0] != 0.0f) atomicAdd(&sc->changed_sum, red[0]);
}

__global__ void k_rc(float* __restrict__ ws, float* __restrict__ out){
  if (threadIdx.x == 0 && blockIdx.x == 0){
    Scal* sc = (Scal*)(ws + OFF_SCAL);
    out[OUT_RC] = sc->changed_sum / 33554432.0f;   // / (S*D)
  }
}

// ================= host =================
extern "C" void kernel_launch(void* const* d_in, const int* in_sizes, int n_in,
                              void* d_out, int out_size, void* d_ws, size_t ws_size,
                              hipStream_t stream) {
  const float* nc    = (const float*)d_in[0];
  const float* qr    = (const float*)d_in[1];
  const float* mem   = (const float*)d_in[2];
  const float* at    = (const float*)d_in[3];
  const int*   step  = (const int*)  d_in[4];
  const float* sr_w1 = (const float*)d_in[5];
  const float* sr_b1 = (const float*)d_in[6];
  const float* sr_g  = (const float*)d_in[7];
  const float* sr_be = (const float*)d_in[8];
  const float* sr_w2 = (const float*)d_in[9];
  const float* sr_b2 = (const float*)d_in[10];
  const float* sn_w  = (const float*)d_in[11];
  const float* sn_b  = (const float*)d_in[12];
  const float* sg_w  = (const float*)d_in[13];
  const float* sg_b  = (const float*)d_in[14];
  const float* el_w  = (const float*)d_in[15];
  const float* el_b  = (const float*)d_in[16];
  const float* ec_w  = (const float*)d_in[17];
  const float* ec_b  = (const float*)d_in[18];
  const float* eg_w  = (const float*)d_in[19];
  const float* eg_b  = (const float*)d_in[20];
  const float* dd_w1 = (const float*)d_in[21];
  const float* dd_b1 = (const float*)d_in[22];
  const float* dd_w2 = (const float*)d_in[23];
  const float* dd_b2 = (const float*)d_in[24];
  const float* ds_w1 = (const float*)d_in[25];
  const float* ds_b1 = (const float*)d_in[26];
  const float* ds_w2 = (const float*)d_in[27];
  const float* ds_b2 = (const float*)d_in[28];
  float* out = (float*)d_out;
  float* ws  = (float*)d_ws;

  k_init     <<<dim3(289), dim3(256), 0, stream>>>(nc, at, ec_w, step, ws, out);
  k_mlp1a    <<<dim3(128), dim3(256), 0, stream>>>(nc, qr, sr_w1, ws);
  k_phase1   <<<dim3(1024), dim3(256), 0, stream>>>(mem, ec_b, eg_w, ws, out);
  k_mlp1b    <<<dim3(65), dim3(256), 0, stream>>>(nc, qr, sr_b1, sr_g, sr_be,
                                                  sr_w2, sr_b2, sn_w, sn_b, sg_w, sg_b, ws, out);
  k_scan     <<<dim3(512), dim3(256), 0, stream>>>(at, step, ws);
  k_victimfix<<<dim3(1), dim3(256), 0, stream>>>(ec_b, eg_w, ws, out);
  k_top3     <<<dim3(64), dim3(256), 0, stream>>>(ws);
  k_mlp2     <<<dim3(256), dim3(256), 0, stream>>>(nc, dd_w1, ds_w1, ws, out);
  k_pairfin  <<<dim3(192), dim3(256), 0, stream>>>(nc, dd_b1, dd_w2, dd_b2,
                                                   ds_b1, ds_w2, ds_b2, ws, out);
  k_scatter  <<<dim3(8), dim3(64), 0, stream>>>(ws, out);
  k_erase    <<<dim3(64), dim3(256), 0, stream>>>(step, el_w, el_b, eg_w, eg_b, ws, out);
  k_decide   <<<dim3(1), dim3(64), 0, stream>>>(nc, ws);
  k_finalout <<<dim3(65), dim3(256), 0, stream>>>(step, ws, out);
  k_diff     <<<dim3(64), dim3(256), 0, stream>>>(mem, ws, out);
  k_rc       <<<dim3(1), dim3(64), 0, stream>>>(ws, out);
}